// Round 1
// baseline (681.982 us; speedup 1.0000x reference)
//
#include <hip/hip_runtime.h>
#include <stdint.h>

#define BATCH 2
#define NANCH 100000
#define NCLS 80
#define TOPK 300
#define BINS 128
#define K1_CHUNKS 128                         // chunks per image
#define K1_BLOCKS (BATCH * K1_CHUNKS)         // 256
#define ELEMS_PER_IMG (NANCH * NCLS)          // 8,000,000
#define ELEMS_PER_CHUNK (ELEMS_PER_IMG / K1_CHUNKS)   // 62,500
#define F4_PER_CHUNK (ELEMS_PER_CHUNK / 4)            // 15,625
#define NSLICE (BATCH * NCLS)                 // 160
#define CAND 2048
#define FLATN (NCLS * TOPK)                   // 24000

// ---------- IoU, bit-exact vs reference (no FMA contraction) ----------
__device__ __forceinline__ bool iou_gt_half(float4 a, float4 b) {
#pragma clang fp contract(off)
    // layout: x=y1, y=x1, z=y2, w=x2
    float areaA = (a.z - a.x) * (a.w - a.y);
    float areaB = (b.z - b.x) * (b.w - b.y);
    float ty = fmaxf(a.x, b.x);
    float tx = fmaxf(a.y, b.y);
    float by = fminf(a.z, b.z);
    float bx = fminf(a.w, b.w);
    float hh = fmaxf(by - ty, 0.0f);
    float ww = fmaxf(bx - tx, 0.0f);
    float inter = hh * ww;
    float un = (areaA + areaB) - inter;
    float iou = inter / fmaxf(un, 1e-8f);
    return iou > 0.5f;
}

// ---------- K1: per-chunk histograms (coalesced scan #1) ----------
__global__ __launch_bounds__(512) void k1_hist(const float* __restrict__ cls,
                                               uint32_t* __restrict__ phist) {
    __shared__ uint32_t h[NCLS * BINS];  // 40 KB
    const int tid = threadIdx.x;
    for (int i = tid; i < NCLS * BINS; i += 512) h[i] = 0;
    __syncthreads();
    const int blk = blockIdx.x;
    const int b  = blk / K1_CHUNKS;
    const int ck = blk % K1_CHUNKS;
    const int e0 = ck * ELEMS_PER_CHUNK;
    const float4* p = reinterpret_cast<const float4*>(cls + (size_t)b * ELEMS_PER_IMG + e0);
    for (int t = tid; t < F4_PER_CHUNK; t += 512) {
        float4 v = p[t];
        int e = e0 + t * 4;
        int c = e % NCLS;       // multiple of 4; c..c+3 same anchor
        float s;
        s = v.x; if (s > 0.05f) { int bn = min((int)(s * 128.0f), 127); atomicAdd(&h[(c + 0) * BINS + bn], 1u); }
        s = v.y; if (s > 0.05f) { int bn = min((int)(s * 128.0f), 127); atomicAdd(&h[(c + 1) * BINS + bn], 1u); }
        s = v.z; if (s > 0.05f) { int bn = min((int)(s * 128.0f), 127); atomicAdd(&h[(c + 2) * BINS + bn], 1u); }
        s = v.w; if (s > 0.05f) { int bn = min((int)(s * 128.0f), 127); atomicAdd(&h[(c + 3) * BINS + bn], 1u); }
    }
    __syncthreads();
    uint32_t* outp = phist + (size_t)blk * (NCLS * BINS);
    for (int i = tid; i < NCLS * BINS; i += 512) outp[i] = h[i];
}

// ---------- K2: reduce partials, find cutoff bin per slice ----------
__global__ __launch_bounds__(BINS) void k2_cutoff(const uint32_t* __restrict__ phist,
                                                  uint32_t* __restrict__ cutoff) {
    __shared__ uint32_t h[BINS];
    const int t = threadIdx.x;           // bin
    const int slice = blockIdx.x;        // b*NCLS + c
    const int b = slice / NCLS, c = slice % NCLS;
    uint32_t sum = 0;
    for (int ck = 0; ck < K1_CHUNKS; ++ck)
        sum += phist[((size_t)(b * K1_CHUNKS + ck) * NCLS + c) * BINS + t];
    h[t] = sum;
    __syncthreads();
    if (t == 0) {
        uint32_t cum = 0;
        int T = 0;
        for (int d = BINS - 1; d >= 0; --d) {
            if (cum + h[d] >= (uint32_t)TOPK) { T = d; break; }
            cum += h[d];
        }
        // if total < TOPK: loop never breaks, T stays 0 -> collect everything
        cutoff[slice] = (uint32_t)T;
    }
}

// ---------- K3: collect candidate keys (coalesced scan #2) ----------
__global__ __launch_bounds__(256) void k3_collect(const float* __restrict__ cls,
                                                  const uint32_t* __restrict__ cutoff,
                                                  uint32_t* __restrict__ ccount,
                                                  uint64_t* __restrict__ cand) {
    __shared__ uint32_t cutL[NSLICE];
    for (int i = threadIdx.x; i < NSLICE; i += 256) cutL[i] = cutoff[i];
    __syncthreads();
    const int total4 = (BATCH * ELEMS_PER_IMG) / 4;  // 4,000,000
    const float4* p = reinterpret_cast<const float4*>(cls);
    for (int i = blockIdx.x * 256 + threadIdx.x; i < total4; i += gridDim.x * 256) {
        float4 v = p[i];
        uint32_t eg = (uint32_t)i * 4u;
        int b = (eg >= (uint32_t)ELEMS_PER_IMG) ? 1 : 0;
        uint32_t e = eg - (uint32_t)b * (uint32_t)ELEMS_PER_IMG;
        uint32_t n = e / NCLS;
        uint32_t c = e - n * NCLS;
        uint32_t invn = ~n;
        float ss0 = v.x, ss1 = v.y, ss2 = v.z, ss3 = v.w;
        float arr[4] = {ss0, ss1, ss2, ss3};
#pragma unroll
        for (int q = 0; q < 4; ++q) {
            float s = arr[q];
            if (s > 0.05f) {
                int bn = min((int)(s * 128.0f), 127);
                int slice = b * NCLS + (int)c + q;
                if ((uint32_t)bn >= cutL[slice]) {
                    uint32_t slot = atomicAdd(&ccount[slice], 1u);
                    if (slot < CAND)
                        cand[(size_t)slice * CAND + slot] =
                            ((uint64_t)__float_as_uint(s) << 32) | (uint64_t)invn;
                }
            }
        }
    }
}

// ---------- K4: per-slice sort + NMS + stage ----------
__global__ __launch_bounds__(512) void k4_nms(const float* __restrict__ boxes,
                                              const uint32_t* __restrict__ ccount,
                                              const uint64_t* __restrict__ cand,
                                              uint64_t* __restrict__ staged,
                                              int* __restrict__ nsel) {
    __shared__ uint64_t keys[CAND];        // 16 KB
    __shared__ float4 box[TOPK];           // 4.8 KB
    __shared__ uint32_t rowm[TOPK * 10];   // 12 KB, lower-triangular sup bits
    __shared__ uint8_t kept[TOPK];
    const int tid = threadIdx.x;
    const int slice = blockIdx.x;
    const int b = slice / NCLS, c = slice % NCLS;
    const uint32_t cnt = min(ccount[slice], (uint32_t)CAND);
    for (int i = tid; i < CAND; i += 512)
        keys[i] = (i < (int)cnt) ? cand[(size_t)slice * CAND + i] : 0ull;

    // bitonic sort ascending (rank r desc = keys[CAND-1-r])
    for (int k = 2; k <= CAND; k <<= 1) {
        for (int j = k >> 1; j > 0; j >>= 1) {
            __syncthreads();
            for (int i = tid; i < CAND; i += 512) {
                int p = i ^ j;
                if (p > i) {
                    uint64_t a = keys[i], bb = keys[p];
                    if ((a > bb) == ((i & k) == 0)) { keys[i] = bb; keys[p] = a; }
                }
            }
        }
    }
    __syncthreads();

    // gather top-K boxes
    for (int r = tid; r < TOPK; r += 512) {
        uint64_t sk = keys[CAND - 1 - r];
        uint32_t n = sk ? ~(uint32_t)sk : 0u;
        box[r] = reinterpret_cast<const float4*>(boxes)[(size_t)b * NANCH + n];
    }
    for (int i = tid; i < TOPK * 10; i += 512) rowm[i] = 0;
    __syncthreads();

    // pairwise IoU > 0.5, lower triangle only (r2 < r1)
    for (int t = tid; t < TOPK * TOPK; t += 512) {
        int r1 = t / TOPK, r2 = t - r1 * TOPK;
        if (r2 < r1) {
            if (iou_gt_half(box[r1], box[r2]))
                atomicOr(&rowm[r1 * 10 + (r2 >> 5)], 1u << (r2 & 31));
        }
    }
    __syncthreads();

    // greedy NMS, wave 0 only: suppressed_i = rowm[i] & keptMask
    if (tid < 64) {
        uint32_t M = 0;  // lanes 0..9 hold kept-mask words
        for (int i = 0; i < TOPK; ++i) {
            bool valid = keys[CAND - 1 - i] != 0ull;
            uint32_t ov = (tid < 10) ? (rowm[i * 10 + tid] & M) : 0u;
            bool sup = __any(ov != 0u);
            bool keep = valid && !sup;
            if (keep && tid == (i >> 5)) M |= (1u << (i & 31));
            if (tid == 0) kept[i] = keep ? 1 : 0;
        }
    }
    __syncthreads();

    // stage final keys + anchor indices
    for (int r = tid; r < TOPK; r += 512) {
        uint64_t sk = keys[CAND - 1 - r];
        uint32_t flat = (uint32_t)c * TOPK + (uint32_t)r;
        uint32_t n = sk ? ~(uint32_t)sk : 0u;
        nsel[(size_t)b * FLATN + flat] = (int)n;
        staged[(size_t)b * FLATN + flat] =
            (kept[r] ? ((sk & 0xFFFFFFFF00000000ull) | (uint64_t)(~flat)) : 0ull);
    }
}

// ---------- K5: per-image radix-select top-300 of 24000 + sort + write ----------
__global__ __launch_bounds__(1024) void k5_final(const float* __restrict__ boxes,
                                                 const uint64_t* __restrict__ staged,
                                                 const int* __restrict__ nsel,
                                                 float* __restrict__ out) {
    __shared__ uint32_t hist[256];
    __shared__ uint64_t sel[512];
    __shared__ uint32_t selCount;
    __shared__ uint64_t prefixS;
    __shared__ int needS;
    __shared__ int doneS;
    const int tid = threadIdx.x;
    const int b = blockIdx.x;
    const uint64_t* keys = staged + (size_t)b * FLATN;
    if (tid == 0) { prefixS = 0; needS = TOPK; doneS = 0; selCount = 0; }
    __syncthreads();

    for (int r = 7; r >= 0; --r) {
        if (doneS) break;  // uniform (synced)
        for (int i = tid; i < 256; i += 1024) hist[i] = 0;
        __syncthreads();
        const int shift = r * 8;
        const uint64_t pref = prefixS;
        for (int i = tid; i < FLATN; i += 1024) {
            uint64_t kk = keys[i];
            if (kk != 0ull) {
                bool match = (r == 7) || (((kk ^ pref) >> (shift + 8)) == 0ull);
                if (match) atomicAdd(&hist[(uint32_t)(kk >> shift) & 255u], 1u);
            }
        }
        __syncthreads();
        if (tid == 0) {
            int need = needS;
            if (r == 7) {
                uint32_t tot = 0;
                for (int d = 0; d < 256; ++d) tot += hist[d];
                if (tot < (uint32_t)need) { prefixS = 1; doneS = 1; }
            }
            if (!doneS) {
                uint32_t cum = 0;
                int pick = 0;
                for (int d = 255; d >= 0; --d) {
                    if (cum + hist[d] >= (uint32_t)need) { pick = d; need -= (int)cum; break; }
                    cum += hist[d];
                }
                prefixS = pref | ((uint64_t)pick << shift);
                needS = need;
            }
        }
        __syncthreads();
    }
    const uint64_t thresh = prefixS;

    // collect keys >= thresh
    for (int i = tid; i < FLATN; i += 1024) {
        uint64_t kk = keys[i];
        if (kk != 0ull && kk >= thresh) {
            uint32_t pos = atomicAdd(&selCount, 1u);
            if (pos < 512) sel[pos] = kk;
        }
    }
    __syncthreads();
    uint32_t sc = min(selCount, 512u);
    for (int i = tid; i < 512; i += 1024)
        if (i >= (int)sc) sel[i] = 0ull;

    // bitonic sort 512 ascending
    for (int k = 2; k <= 512; k <<= 1) {
        for (int j = k >> 1; j > 0; j >>= 1) {
            __syncthreads();
            for (int i = tid; i < 512; i += 1024) {
                int p = i ^ j;
                if (p > i) {
                    uint64_t a = sel[i], bb = sel[p];
                    if ((a > bb) == ((i & k) == 0)) { sel[i] = bb; sel[p] = a; }
                }
            }
        }
    }
    __syncthreads();

    float* outBoxes = out;                             // [B][TOPK][4]
    float* outScores = out + BATCH * TOPK * 4;         // [B][TOPK]
    float* outLabels = out + BATCH * TOPK * 4 + BATCH * TOPK;
    for (int r0 = tid; r0 < TOPK; r0 += 1024) {
        uint64_t kk = sel[511 - r0];
        if (kk != 0ull) {
            uint32_t flat = ~(uint32_t)kk;
            uint32_t c = flat / TOPK;
            uint32_t n = (uint32_t)nsel[(size_t)b * FLATN + flat];
            float4 bx = reinterpret_cast<const float4*>(boxes)[(size_t)b * NANCH + n];
            reinterpret_cast<float4*>(outBoxes)[(size_t)b * TOPK + r0] = bx;
            outScores[b * TOPK + r0] = __uint_as_float((uint32_t)(kk >> 32));
            outLabels[b * TOPK + r0] = (float)c;
        } else {
            reinterpret_cast<float4*>(outBoxes)[(size_t)b * TOPK + r0] =
                make_float4(-1.0f, -1.0f, -1.0f, -1.0f);
            outScores[b * TOPK + r0] = -1.0f;
            outLabels[b * TOPK + r0] = -1.0f;
        }
    }
}

extern "C" void kernel_launch(void* const* d_in, const int* in_sizes, int n_in,
                              void* d_out, int out_size, void* d_ws, size_t ws_size,
                              hipStream_t stream) {
    const float* boxes = (const float*)d_in[0];          // [2,100000,4]
    const float* cls   = (const float*)d_in[1];          // [2,100000,80]
    float* out = (float*)d_out;                          // 3600 floats
    char* ws = (char*)d_ws;

    size_t off = 0;
    uint32_t* phist = (uint32_t*)(ws + off);
    off += (size_t)K1_BLOCKS * NCLS * BINS * 4;          // 10,485,760
    uint32_t* cutoff = (uint32_t*)(ws + off); off += 4096;
    uint32_t* ccount = (uint32_t*)(ws + off); off += 4096;
    uint64_t* cand = (uint64_t*)(ws + off);
    off += (size_t)NSLICE * CAND * 8;                    // 2,621,440
    uint64_t* staged = (uint64_t*)(ws + off);
    off += (size_t)BATCH * FLATN * 8;                    // 384,000
    int* nsel = (int*)(ws + off);
    off += (size_t)BATCH * FLATN * 4;                    // 192,000

    hipMemsetAsync(ccount, 0, NSLICE * 4, stream);
    k1_hist<<<K1_BLOCKS, 512, 0, stream>>>(cls, phist);
    k2_cutoff<<<NSLICE, BINS, 0, stream>>>(phist, cutoff);
    k3_collect<<<2048, 256, 0, stream>>>(cls, cutoff, ccount, cand);
    k4_nms<<<NSLICE, 512, 0, stream>>>(boxes, ccount, cand, staged, nsel);
    k5_final<<<BATCH, 1024, 0, stream>>>(boxes, staged, nsel, out);
}

// Round 2
// 616.105 us; speedup vs baseline: 1.1069x; 1.1069x over previous
//
#include <hip/hip_runtime.h>
#include <stdint.h>

#define BATCH 2
#define NANCH 100000
#define NCLS 80
#define TOPK 300
#define NSLICE (BATCH * NCLS)                 // 160
#define CAND 2048
#define FLATN (NCLS * TOPK)                   // 24000
#define ELEMS_PER_IMG (NANCH * NCLS)          // 8,000,000
#define CUT 0.992f                            // < 127/128; expected ~781 cand/slice on bench data

// ---------- IoU, bit-exact vs reference (no FMA contraction) ----------
__device__ __forceinline__ bool iou_gt_half(float4 a, float4 b) {
#pragma clang fp contract(off)
    float areaA = (a.z - a.x) * (a.w - a.y);
    float areaB = (b.z - b.x) * (b.w - b.y);
    float ty = fmaxf(a.x, b.x);
    float tx = fmaxf(a.y, b.y);
    float by = fminf(a.z, b.z);
    float bx = fminf(a.w, b.w);
    float hh = fmaxf(by - ty, 0.0f);
    float ww = fmaxf(bx - tx, 0.0f);
    float inter = hh * ww;
    float un = (areaA + areaB) - inter;
    float iou = inter / fmaxf(un, 1e-8f);
    return iou > 0.5f;
}

// ---------- K1: streaming collect with fixed cutoff (no LDS in hot path) ----------
__global__ __launch_bounds__(256) void k1_collect(const float* __restrict__ cls,
                                                  uint32_t* __restrict__ ccount,
                                                  uint64_t* __restrict__ cand) {
    const int total4 = (BATCH * ELEMS_PER_IMG) / 4;  // 4,000,000
    const float4* p = reinterpret_cast<const float4*>(cls);
    for (int i = blockIdx.x * 256 + threadIdx.x; i < total4; i += gridDim.x * 256) {
        float4 v = p[i];
        if (v.x >= CUT || v.y >= CUT || v.z >= CUT || v.w >= CUT) {
            uint32_t eg = (uint32_t)i * 4u;
            int b = (eg >= (uint32_t)ELEMS_PER_IMG) ? 1 : 0;
            uint32_t e = eg - (uint32_t)b * (uint32_t)ELEMS_PER_IMG;
            uint32_t n = e / NCLS;
            uint32_t c = e - n * NCLS;
            float arr[4] = {v.x, v.y, v.z, v.w};
#pragma unroll
            for (int q = 0; q < 4; ++q) {
                float s = arr[q];
                if (s >= CUT) {
                    int slice = b * NCLS + (int)c + q;
                    uint32_t slot = atomicAdd(&ccount[slice], 1u);
                    if (slot < CAND)
                        cand[(size_t)slice * CAND + slot] =
                            ((uint64_t)__float_as_uint(s) << 32) | (uint64_t)(~n);
                }
            }
        }
    }
}

// ---------- K2: generic fixup (exits immediately when K1's superset is valid) ----------
__global__ __launch_bounds__(256) void k2_fixup(const float* __restrict__ cls,
                                                uint32_t* __restrict__ ccount,
                                                uint64_t* __restrict__ cand) {
    const int slice = blockIdx.x;
    const uint32_t cnt0 = ccount[slice];
    if (cnt0 >= (uint32_t)TOPK && cnt0 <= (uint32_t)CAND) return;  // fast path
    // Slow path (not expected on bench data): exact per-slice rescan.
    const int b = slice / NCLS, c = slice % NCLS;
    const float* col = cls + (size_t)b * ELEMS_PER_IMG + c;
    __shared__ uint32_t h[128];
    __shared__ uint32_t nvalid;
    __shared__ int Tb;
    const int tid = threadIdx.x;
    for (int i = tid; i < 128; i += 256) h[i] = 0;
    if (tid == 0) nvalid = 0;
    __syncthreads();
    for (int i = tid; i < NANCH; i += 256) {
        float s = col[(size_t)i * NCLS];
        if (s > 0.05f) {
            int bn = min((int)(fminf(s, 0.9999999f) * 128.0f), 127);
            atomicAdd(&h[bn], 1u);
            atomicAdd(&nvalid, 1u);
        }
    }
    __syncthreads();
    if (tid == 0) {
        uint32_t need = min((uint32_t)TOPK, nvalid);
        uint32_t cum = 0;
        int T = 0;
        if (need > 0) {
            for (int d = 127; d >= 0; --d) {
                if (cum + h[d] >= need) { T = d; break; }
                cum += h[d];
            }
        } else {
            T = 128;  // nothing valid -> collect nothing
        }
        Tb = T;
        ccount[slice] = 0;
    }
    __syncthreads();
    const int T = Tb;
    for (int i = tid; i < NANCH; i += 256) {
        float s = col[(size_t)i * NCLS];
        if (s > 0.05f) {
            int bn = min((int)(fminf(s, 0.9999999f) * 128.0f), 127);
            if (bn >= T) {
                uint32_t slot = atomicAdd(&ccount[slice], 1u);
                if (slot < CAND)
                    cand[(size_t)slice * CAND + slot] =
                        ((uint64_t)__float_as_uint(s) << 32) | (uint64_t)(~(uint32_t)i);
            }
        }
    }
}

// ---------- K3: per-slice sort + NMS + stage ----------
__global__ __launch_bounds__(512) void k3_nms(const float* __restrict__ boxes,
                                              const uint32_t* __restrict__ ccount,
                                              const uint64_t* __restrict__ cand,
                                              uint64_t* __restrict__ staged,
                                              int* __restrict__ nsel) {
    __shared__ uint64_t keys[CAND];        // 16 KB
    __shared__ float4 box[TOPK];           // 4.8 KB
    __shared__ uint32_t rowm[TOPK * 10];   // 12 KB
    __shared__ uint8_t kept[TOPK];
    const int tid = threadIdx.x;
    const int slice = blockIdx.x;
    const int b = slice / NCLS, c = slice % NCLS;
    const uint32_t cnt = min(ccount[slice], (uint32_t)CAND);
    const int SN = (cnt <= 1024u) ? 1024 : 2048;   // dynamic sort size (uniform per block)
    for (int i = tid; i < SN; i += 512)
        keys[i] = (i < (int)cnt) ? cand[(size_t)slice * CAND + i] : 0ull;

    // bitonic sort ascending (rank r desc = keys[SN-1-r])
    for (int k = 2; k <= SN; k <<= 1) {
        for (int j = k >> 1; j > 0; j >>= 1) {
            __syncthreads();
            for (int i = tid; i < SN; i += 512) {
                int p = i ^ j;
                if (p > i) {
                    uint64_t a = keys[i], bb = keys[p];
                    if ((a > bb) == ((i & k) == 0)) { keys[i] = bb; keys[p] = a; }
                }
            }
        }
    }
    __syncthreads();

    // gather top-K boxes
    for (int r = tid; r < TOPK; r += 512) {
        uint64_t sk = keys[SN - 1 - r];
        uint32_t n = sk ? ~(uint32_t)sk : 0u;
        box[r] = reinterpret_cast<const float4*>(boxes)[(size_t)b * NANCH + n];
    }
    for (int i = tid; i < TOPK * 10; i += 512) rowm[i] = 0;
    __syncthreads();

    // pairwise IoU > 0.5, lower triangle only (r2 < r1)
    for (int t = tid; t < TOPK * TOPK; t += 512) {
        int r1 = t / TOPK, r2 = t - r1 * TOPK;
        if (r2 < r1) {
            if (iou_gt_half(box[r1], box[r2]))
                atomicOr(&rowm[r1 * 10 + (r2 >> 5)], 1u << (r2 & 31));
        }
    }
    __syncthreads();

    // greedy NMS, wave 0 only
    if (tid < 64) {
        uint32_t M = 0;
        for (int i = 0; i < TOPK; ++i) {
            bool valid = keys[SN - 1 - i] != 0ull;
            uint32_t ov = (tid < 10) ? (rowm[i * 10 + tid] & M) : 0u;
            bool sup = __any(ov != 0u);
            bool keep = valid && !sup;
            if (keep && tid == (i >> 5)) M |= (1u << (i & 31));
            if (tid == 0) kept[i] = keep ? 1 : 0;
        }
    }
    __syncthreads();

    // stage final keys + anchor indices
    for (int r = tid; r < TOPK; r += 512) {
        uint64_t sk = keys[SN - 1 - r];
        uint32_t flat = (uint32_t)c * TOPK + (uint32_t)r;
        uint32_t n = sk ? ~(uint32_t)sk : 0u;
        nsel[(size_t)b * FLATN + flat] = (int)n;
        staged[(size_t)b * FLATN + flat] =
            (kept[r] ? ((sk & 0xFFFFFFFF00000000ull) | (uint64_t)(~flat)) : 0ull);
    }
}

// ---------- K4: per-image radix-select top-300 of 24000 + sort + write ----------
__global__ __launch_bounds__(1024) void k4_final(const float* __restrict__ boxes,
                                                 const uint64_t* __restrict__ staged,
                                                 const int* __restrict__ nsel,
                                                 float* __restrict__ out) {
    __shared__ uint32_t hist[256];
    __shared__ uint64_t sel[512];
    __shared__ uint32_t selCount;
    __shared__ uint64_t prefixS;
    __shared__ int needS;
    __shared__ int doneS;
    const int tid = threadIdx.x;
    const int b = blockIdx.x;
    const uint64_t* keys = staged + (size_t)b * FLATN;
    if (tid == 0) { prefixS = 0; needS = TOPK; doneS = 0; selCount = 0; }
    __syncthreads();

    for (int r = 7; r >= 0; --r) {
        if (doneS) break;  // uniform
        for (int i = tid; i < 256; i += 1024) hist[i] = 0;
        __syncthreads();
        const int shift = r * 8;
        const uint64_t pref = prefixS;
        for (int i = tid; i < FLATN; i += 1024) {
            uint64_t kk = keys[i];
            if (kk != 0ull) {
                bool match = (r == 7) || (((kk ^ pref) >> (shift + 8)) == 0ull);
                if (match) atomicAdd(&hist[(uint32_t)(kk >> shift) & 255u], 1u);
            }
        }
        __syncthreads();
        if (tid == 0) {
            int need = needS;
            if (r == 7) {
                uint32_t tot = 0;
                for (int d = 0; d < 256; ++d) tot += hist[d];
                if (tot < (uint32_t)need) { prefixS = 1; doneS = 1; }
            }
            if (!doneS) {
                uint32_t cum = 0;
                for (int d = 255; d >= 0; --d) {
                    if (cum + hist[d] >= (uint32_t)need) {
                        int newNeed = need - (int)cum;
                        prefixS = pref | ((uint64_t)d << shift);
                        needS = newNeed;
                        if ((int)hist[d] == newNeed) doneS = 1;  // whole bucket taken; low bytes 0
                        break;
                    }
                    cum += hist[d];
                }
            }
        }
        __syncthreads();
    }
    const uint64_t thresh = prefixS;

    for (int i = tid; i < FLATN; i += 1024) {
        uint64_t kk = keys[i];
        if (kk != 0ull && kk >= thresh) {
            uint32_t pos = atomicAdd(&selCount, 1u);
            if (pos < 512) sel[pos] = kk;
        }
    }
    __syncthreads();
    uint32_t sc = min(selCount, 512u);
    for (int i = tid; i < 512; i += 1024)
        if (i >= (int)sc) sel[i] = 0ull;

    for (int k = 2; k <= 512; k <<= 1) {
        for (int j = k >> 1; j > 0; j >>= 1) {
            __syncthreads();
            for (int i = tid; i < 512; i += 1024) {
                int p = i ^ j;
                if (p > i) {
                    uint64_t a = sel[i], bb = sel[p];
                    if ((a > bb) == ((i & k) == 0)) { sel[i] = bb; sel[p] = a; }
                }
            }
        }
    }
    __syncthreads();

    float* outBoxes = out;                             // [B][TOPK][4]
    float* outScores = out + BATCH * TOPK * 4;         // [B][TOPK]
    float* outLabels = out + BATCH * TOPK * 4 + BATCH * TOPK;
    for (int r0 = tid; r0 < TOPK; r0 += 1024) {
        uint64_t kk = sel[511 - r0];
        if (kk != 0ull) {
            uint32_t flat = ~(uint32_t)kk;
            uint32_t c = flat / TOPK;
            uint32_t n = (uint32_t)nsel[(size_t)b * FLATN + flat];
            float4 bx = reinterpret_cast<const float4*>(boxes)[(size_t)b * NANCH + n];
            reinterpret_cast<float4*>(outBoxes)[(size_t)b * TOPK + r0] = bx;
            outScores[b * TOPK + r0] = __uint_as_float((uint32_t)(kk >> 32));
            outLabels[b * TOPK + r0] = (float)c;
        } else {
            reinterpret_cast<float4*>(outBoxes)[(size_t)b * TOPK + r0] =
                make_float4(-1.0f, -1.0f, -1.0f, -1.0f);
            outScores[b * TOPK + r0] = -1.0f;
            outLabels[b * TOPK + r0] = -1.0f;
        }
    }
}

extern "C" void kernel_launch(void* const* d_in, const int* in_sizes, int n_in,
                              void* d_out, int out_size, void* d_ws, size_t ws_size,
                              hipStream_t stream) {
    const float* boxes = (const float*)d_in[0];          // [2,100000,4]
    const float* cls   = (const float*)d_in[1];          // [2,100000,80]
    float* out = (float*)d_out;                          // 3600 floats
    char* ws = (char*)d_ws;

    size_t off = 0;
    uint32_t* ccount = (uint32_t*)(ws + off); off += 4096;
    uint64_t* cand = (uint64_t*)(ws + off);
    off += (size_t)NSLICE * CAND * 8;                    // 2,621,440
    uint64_t* staged = (uint64_t*)(ws + off);
    off += (size_t)BATCH * FLATN * 8;                    // 384,000
    int* nsel = (int*)(ws + off);
    off += (size_t)BATCH * FLATN * 4;                    // 192,000

    hipMemsetAsync(ccount, 0, NSLICE * 4, stream);
    k1_collect<<<2048, 256, 0, stream>>>(cls, ccount, cand);
    k2_fixup<<<NSLICE, 256, 0, stream>>>(cls, ccount, cand);
    k3_nms<<<NSLICE, 512, 0, stream>>>(boxes, ccount, cand, staged, nsel);
    k4_final<<<BATCH, 1024, 0, stream>>>(boxes, staged, nsel, out);
}

// Round 5
// 299.669 us; speedup vs baseline: 2.2758x; 2.0560x over previous
//
#include <hip/hip_runtime.h>
#include <stdint.h>

#define BATCH 2
#define NANCH 100000
#define NCLS 80
#define TOPK 300
#define NSLICE (BATCH * NCLS)                 // 160
#define CAND 2048
#define FLATN (NCLS * TOPK)                   // 24000
#define ELEMS_PER_IMG (NANCH * NCLS)          // 8,000,000
#define F4TOTAL ((BATCH * ELEMS_PER_IMG) / 4) // 4,000,000
#define CUT 0.992f                            // expected ~800 cand/slice on uniform data
#define CHUNK_F4 2048                         // 256 thr x 8 f4
#define NBLK ((F4TOTAL + CHUNK_F4 - 1) / CHUNK_F4)  // 1954
#define NBPAD 2048

// ---------- IoU, bit-exact vs reference (no FMA contraction) ----------
__device__ __forceinline__ bool iou_gt_half(float4 a, float4 b) {
#pragma clang fp contract(off)
    float areaA = (a.z - a.x) * (a.w - a.y);
    float areaB = (b.z - b.x) * (b.w - b.y);
    float ty = fmaxf(a.x, b.x);
    float tx = fmaxf(a.y, b.y);
    float by = fminf(a.z, b.z);
    float bx = fminf(a.w, b.w);
    float hh = fmaxf(by - ty, 0.0f);
    float ww = fmaxf(bx - tx, 0.0f);
    float inter = hh * ww;
    float un = (areaA + areaB) - inter;
    float iou = inter / fmaxf(un, 1e-8f);
    return iou > 0.5f;
}

// ---------- K1: per-block per-slice counts (no global atomics) ----------
__global__ __launch_bounds__(256) void k1_count(const float* __restrict__ cls,
                                                uint32_t* __restrict__ blockcnt) {
    __shared__ uint32_t cnt[NSLICE];
    const int tid = threadIdx.x, blk = blockIdx.x;
    for (int i = tid; i < NSLICE; i += 256) cnt[i] = 0;
    __syncthreads();
    const float4* p = reinterpret_cast<const float4*>(cls);
    const int base = blk * CHUNK_F4;
#pragma unroll
    for (int j = 0; j < 8; ++j) {
        int i = base + j * 256 + tid;
        if (i < F4TOTAL) {
            float4 v = p[i];
            if (v.x >= CUT || v.y >= CUT || v.z >= CUT || v.w >= CUT) {
                uint32_t eg = (uint32_t)i * 4u;
                int b = (eg >= (uint32_t)ELEMS_PER_IMG) ? 1 : 0;
                uint32_t e = eg - (uint32_t)b * (uint32_t)ELEMS_PER_IMG;
                uint32_t c = e % NCLS;
                float arr[4] = {v.x, v.y, v.z, v.w};
#pragma unroll
                for (int q = 0; q < 4; ++q)
                    if (arr[q] >= CUT) atomicAdd(&cnt[b * NCLS + (int)c + q], 1u);
            }
        }
    }
    __syncthreads();
    for (int s = tid; s < NSLICE; s += 256) blockcnt[(size_t)s * NBPAD + blk] = cnt[s];
}

// ---------- K2: per-slice exclusive prefix scan over blocks ----------
__global__ __launch_bounds__(256) void k2_scan(const uint32_t* __restrict__ blockcnt,
                                               uint32_t* __restrict__ blockbase,
                                               uint32_t* __restrict__ ccount) {
    __shared__ uint32_t A[NBPAD], B[NBPAD];
    const int s = blockIdx.x, tid = threadIdx.x;
    for (int i = tid; i < NBPAD; i += 256)
        A[i] = (i >= 1 && i <= NBLK) ? blockcnt[(size_t)s * NBPAD + i - 1] : 0u;
    __syncthreads();
    uint32_t* src = A;
    uint32_t* dst = B;
    for (int off = 1; off < NBPAD; off <<= 1) {
        for (int i = tid; i < NBPAD; i += 256)
            dst[i] = src[i] + ((i >= off) ? src[i - off] : 0u);
        __syncthreads();
        uint32_t* t = src; src = dst; dst = t;
    }
    // src[i] = sum of cnt[0..i-1] = exclusive base for block i; src[NBLK] = total
    for (int i = tid; i < NBLK; i += 256) blockbase[(size_t)s * NBPAD + i] = src[i];
    if (tid == 0) ccount[s] = src[NBLK];
}

// ---------- K3: emit candidates to exclusive reserved positions ----------
__global__ __launch_bounds__(256) void k3_emit(const float* __restrict__ cls,
                                               const uint32_t* __restrict__ blockbase,
                                               uint64_t* __restrict__ cand) {
    __shared__ uint32_t cur[NSLICE];
    const int tid = threadIdx.x, blk = blockIdx.x;
    for (int i = tid; i < NSLICE; i += 256) cur[i] = 0;
    __syncthreads();
    const float4* p = reinterpret_cast<const float4*>(cls);
    const int base = blk * CHUNK_F4;
#pragma unroll
    for (int j = 0; j < 8; ++j) {
        int i = base + j * 256 + tid;
        if (i < F4TOTAL) {
            float4 v = p[i];
            if (v.x >= CUT || v.y >= CUT || v.z >= CUT || v.w >= CUT) {
                uint32_t eg = (uint32_t)i * 4u;
                int b = (eg >= (uint32_t)ELEMS_PER_IMG) ? 1 : 0;
                uint32_t e = eg - (uint32_t)b * (uint32_t)ELEMS_PER_IMG;
                uint32_t n = e / NCLS;
                uint32_t c = e - n * NCLS;
                float arr[4] = {v.x, v.y, v.z, v.w};
#pragma unroll
                for (int q = 0; q < 4; ++q) {
                    float s = arr[q];
                    if (s >= CUT) {
                        int slice = b * NCLS + (int)c + q;
                        uint32_t off = atomicAdd(&cur[slice], 1u);
                        uint32_t pos = blockbase[(size_t)slice * NBPAD + blk] + off;
                        if (pos < CAND)
                            cand[(size_t)slice * CAND + pos] =
                                ((uint64_t)__float_as_uint(s) << 32) | (uint64_t)(~n);
                    }
                }
            }
        }
    }
}

// ---------- K4: generic fixup (exits immediately when superset is valid) ----------
__global__ __launch_bounds__(256) void k4_fixup(const float* __restrict__ cls,
                                                uint32_t* __restrict__ ccount,
                                                uint64_t* __restrict__ cand) {
    const int slice = blockIdx.x;
    const uint32_t cnt0 = ccount[slice];
    if (cnt0 >= (uint32_t)TOPK && cnt0 <= (uint32_t)CAND) return;  // fast path
    const int b = slice / NCLS, c = slice % NCLS;
    const float* col = cls + (size_t)b * ELEMS_PER_IMG + c;
    __shared__ uint32_t h[128];
    __shared__ uint32_t nvalid;
    __shared__ int Tb;
    const int tid = threadIdx.x;
    for (int i = tid; i < 128; i += 256) h[i] = 0;
    if (tid == 0) nvalid = 0;
    __syncthreads();
    for (int i = tid; i < NANCH; i += 256) {
        float s = col[(size_t)i * NCLS];
        if (s > 0.05f) {
            int bn = min((int)(fminf(s, 0.9999999f) * 128.0f), 127);
            atomicAdd(&h[bn], 1u);
            atomicAdd(&nvalid, 1u);
        }
    }
    __syncthreads();
    if (tid == 0) {
        uint32_t need = min((uint32_t)TOPK, nvalid);
        uint32_t cum = 0;
        int T = 0;
        if (need > 0) {
            for (int d = 127; d >= 0; --d) {
                if (cum + h[d] >= need) { T = d; break; }
                cum += h[d];
            }
        } else {
            T = 128;
        }
        Tb = T;
        ccount[slice] = 0;
    }
    __syncthreads();
    const int T = Tb;
    for (int i = tid; i < NANCH; i += 256) {
        float s = col[(size_t)i * NCLS];
        if (s > 0.05f) {
            int bn = min((int)(fminf(s, 0.9999999f) * 128.0f), 127);
            if (bn >= T) {
                uint32_t slot = atomicAdd(&ccount[slice], 1u);
                if (slot < CAND)
                    cand[(size_t)slice * CAND + slot] =
                        ((uint64_t)__float_as_uint(s) << 32) | (uint64_t)(~(uint32_t)i);
            }
        }
    }
}

// ---------- K5: per-slice sort + NMS + stage ----------
__global__ __launch_bounds__(512) void k5_nms(const float* __restrict__ boxes,
                                              const uint32_t* __restrict__ ccount,
                                              const uint64_t* __restrict__ cand,
                                              uint64_t* __restrict__ staged,
                                              int* __restrict__ nsel) {
    __shared__ uint64_t keys[CAND];
    __shared__ float4 box[TOPK];
    __shared__ uint32_t rowm[TOPK * 10];
    __shared__ uint8_t kept[TOPK];
    const int tid = threadIdx.x;
    const int slice = blockIdx.x;
    const int b = slice / NCLS, c = slice % NCLS;
    const uint32_t cnt = min(ccount[slice], (uint32_t)CAND);
    const int SN = (cnt <= 1024u) ? 1024 : 2048;
    for (int i = tid; i < SN; i += 512)
        keys[i] = (i < (int)cnt) ? cand[(size_t)slice * CAND + i] : 0ull;

    for (int k = 2; k <= SN; k <<= 1) {
        for (int j = k >> 1; j > 0; j >>= 1) {
            __syncthreads();
            for (int i = tid; i < SN; i += 512) {
                int p = i ^ j;
                if (p > i) {
                    uint64_t a = keys[i], bb = keys[p];
                    if ((a > bb) == ((i & k) == 0)) { keys[i] = bb; keys[p] = a; }
                }
            }
        }
    }
    __syncthreads();

    for (int r = tid; r < TOPK; r += 512) {
        uint64_t sk = keys[SN - 1 - r];
        uint32_t n = sk ? ~(uint32_t)sk : 0u;
        box[r] = reinterpret_cast<const float4*>(boxes)[(size_t)b * NANCH + n];
    }
    for (int i = tid; i < TOPK * 10; i += 512) rowm[i] = 0;
    __syncthreads();

    for (int t = tid; t < TOPK * TOPK; t += 512) {
        int r1 = t / TOPK, r2 = t - r1 * TOPK;
        if (r2 < r1) {
            if (iou_gt_half(box[r1], box[r2]))
                atomicOr(&rowm[r1 * 10 + (r2 >> 5)], 1u << (r2 & 31));
        }
    }
    __syncthreads();

    if (tid < 64) {
        uint32_t M = 0;
        for (int i = 0; i < TOPK; ++i) {
            bool valid = keys[SN - 1 - i] != 0ull;
            uint32_t ov = (tid < 10) ? (rowm[i * 10 + tid] & M) : 0u;
            bool sup = __any(ov != 0u);
            bool keep = valid && !sup;
            if (keep && tid == (i >> 5)) M |= (1u << (i & 31));
            if (tid == 0) kept[i] = keep ? 1 : 0;
        }
    }
    __syncthreads();

    for (int r = tid; r < TOPK; r += 512) {
        uint64_t sk = keys[SN - 1 - r];
        uint32_t flat = (uint32_t)c * TOPK + (uint32_t)r;
        uint32_t n = sk ? ~(uint32_t)sk : 0u;
        nsel[(size_t)b * FLATN + flat] = (int)n;
        staged[(size_t)b * FLATN + flat] =
            (kept[r] ? ((sk & 0xFFFFFFFF00000000ull) | (uint64_t)(~flat)) : 0ull);
    }
}

// ---------- K6: per-image radix-select top-300 of 24000 + sort + write ----------
__global__ __launch_bounds__(1024) void k6_final(const float* __restrict__ boxes,
                                                 const uint64_t* __restrict__ staged,
                                                 const int* __restrict__ nsel,
                                                 float* __restrict__ out) {
    __shared__ uint32_t hist[256];
    __shared__ uint64_t sel[512];
    __shared__ uint32_t selCount;
    __shared__ uint64_t prefixS;
    __shared__ int needS;
    __shared__ int doneS;
    const int tid = threadIdx.x;
    const int b = blockIdx.x;
    const uint64_t* keys = staged + (size_t)b * FLATN;
    if (tid == 0) { prefixS = 0; needS = TOPK; doneS = 0; selCount = 0; }
    __syncthreads();

    for (int r = 7; r >= 0; --r) {
        if (doneS) break;
        for (int i = tid; i < 256; i += 1024) hist[i] = 0;
        __syncthreads();
        const int shift = r * 8;
        const uint64_t pref = prefixS;
        for (int i = tid; i < FLATN; i += 1024) {
            uint64_t kk = keys[i];
            if (kk != 0ull) {
                bool match = (r == 7) || (((kk ^ pref) >> (shift + 8)) == 0ull);
                if (match) atomicAdd(&hist[(uint32_t)(kk >> shift) & 255u], 1u);
            }
        }
        __syncthreads();
        if (tid == 0) {
            int need = needS;
            if (r == 7) {
                uint32_t tot = 0;
                for (int d = 0; d < 256; ++d) tot += hist[d];
                if (tot < (uint32_t)need) { prefixS = 1; doneS = 1; }
            }
            if (!doneS) {
                uint32_t cum = 0;
                for (int d = 255; d >= 0; --d) {
                    if (cum + hist[d] >= (uint32_t)need) {
                        int newNeed = need - (int)cum;
                        prefixS = pref | ((uint64_t)d << shift);
                        needS = newNeed;
                        if ((int)hist[d] == newNeed) doneS = 1;
                        break;
                    }
                    cum += hist[d];
                }
            }
        }
        __syncthreads();
    }
    const uint64_t thresh = prefixS;

    for (int i = tid; i < FLATN; i += 1024) {
        uint64_t kk = keys[i];
        if (kk != 0ull && kk >= thresh) {
            uint32_t pos = atomicAdd(&selCount, 1u);
            if (pos < 512) sel[pos] = kk;
        }
    }
    __syncthreads();
    uint32_t sc = min(selCount, 512u);
    for (int i = tid; i < 512; i += 1024)
        if (i >= (int)sc) sel[i] = 0ull;

    for (int k = 2; k <= 512; k <<= 1) {
        for (int j = k >> 1; j > 0; j >>= 1) {
            __syncthreads();
            for (int i = tid; i < 512; i += 1024) {
                int p = i ^ j;
                if (p > i) {
                    uint64_t a = sel[i], bb = sel[p];
                    if ((a > bb) == ((i & k) == 0)) { sel[i] = bb; sel[p] = a; }
                }
            }
        }
    }
    __syncthreads();

    float* outBoxes = out;
    float* outScores = out + BATCH * TOPK * 4;
    float* outLabels = out + BATCH * TOPK * 4 + BATCH * TOPK;
    for (int r0 = tid; r0 < TOPK; r0 += 1024) {
        uint64_t kk = sel[511 - r0];
        if (kk != 0ull) {
            uint32_t flat = ~(uint32_t)kk;
            uint32_t c = flat / TOPK;
            uint32_t n = (uint32_t)nsel[(size_t)b * FLATN + flat];
            float4 bx = reinterpret_cast<const float4*>(boxes)[(size_t)b * NANCH + n];
            reinterpret_cast<float4*>(outBoxes)[(size_t)b * TOPK + r0] = bx;
            outScores[b * TOPK + r0] = __uint_as_float((uint32_t)(kk >> 32));
            outLabels[b * TOPK + r0] = (float)c;
        } else {
            reinterpret_cast<float4*>(outBoxes)[(size_t)b * TOPK + r0] =
                make_float4(-1.0f, -1.0f, -1.0f, -1.0f);
            outScores[b * TOPK + r0] = -1.0f;
            outLabels[b * TOPK + r0] = -1.0f;
        }
    }
}

extern "C" void kernel_launch(void* const* d_in, const int* in_sizes, int n_in,
                              void* d_out, int out_size, void* d_ws, size_t ws_size,
                              hipStream_t stream) {
    const float* boxes = (const float*)d_in[0];          // [2,100000,4]
    const float* cls   = (const float*)d_in[1];          // [2,100000,80]
    float* out = (float*)d_out;                          // 3600 floats
    char* ws = (char*)d_ws;

    size_t off = 0;
    uint32_t* blockcnt = (uint32_t*)(ws + off);
    off += (size_t)NSLICE * NBPAD * 4;                   // 1,310,720
    uint32_t* blockbase = (uint32_t*)(ws + off);
    off += (size_t)NSLICE * NBPAD * 4;                   // 1,310,720
    uint32_t* ccount = (uint32_t*)(ws + off); off += 4096;
    uint64_t* cand = (uint64_t*)(ws + off);
    off += (size_t)NSLICE * CAND * 8;                    // 2,621,440
    uint64_t* staged = (uint64_t*)(ws + off);
    off += (size_t)BATCH * FLATN * 8;                    // 384,000
    int* nsel = (int*)(ws + off);
    off += (size_t)BATCH * FLATN * 4;                    // 192,000

    k1_count<<<NBLK, 256, 0, stream>>>(cls, blockcnt);
    k2_scan<<<NSLICE, 256, 0, stream>>>(blockcnt, blockbase, ccount);
    k3_emit<<<NBLK, 256, 0, stream>>>(cls, blockbase, cand);
    k4_fixup<<<NSLICE, 256, 0, stream>>>(cls, ccount, cand);
    k5_nms<<<NSLICE, 512, 0, stream>>>(boxes, ccount, cand, staged, nsel);
    k6_final<<<BATCH, 1024, 0, stream>>>(boxes, staged, nsel, out);
}